// Round 9
// baseline (721.492 us; speedup 1.0000x reference)
//
#include <hip/hip_runtime.h>
#include <hip/hip_bf16.h>
#include <math.h>

#define B_SZ 1024
#define NMAX 21
#define NN 441            // 21*21
#define HNF 256
#define TOT_ROWS (B_SZ * NN)   // 451584
#define TILES_PER_BATCH 7      // 441 = 7*63
#define BMV 63                 // valid rows per tile (row 63 is pad)

typedef short short8 __attribute__((ext_vector_type(8)));
typedef float float4v __attribute__((ext_vector_type(4)));

__device__ __forceinline__ float softplus_f(float x) {
    return fmaxf(x, 0.f) + log1pf(expf(-fabsf(x)));
}

__device__ __forceinline__ unsigned short f2bf(float x) {
    union { float f; unsigned int u; } v; v.f = x;
    unsigned int r = v.u + 0x7FFFu + ((v.u >> 16) & 1u);   // RNE
    return (unsigned short)(r >> 16);
}

// hardware packed fp32->bf16 (v_cvt_pk_bf16_f32), RNE
__device__ __forceinline__ unsigned pk_bf16(float lo, float hi) {
    __hip_bfloat162 h = __float22bfloat162_rn(float2{lo, hi});
    return *reinterpret_cast<unsigned*>(&h);
}

// wave-uniform broadcast of lane q via SGPR (readlane), avoids ds_bpermute
__device__ __forceinline__ float bcast(float v, int q) {
    int i = __builtin_amdgcn_readlane(__builtin_bit_cast(int, v), q);
    return __builtin_bit_cast(float, i);
}

// fast tanh for x>=0: 1 - 2/(exp2(x*2log2e)+1). v_exp/v_rcp approx (~1e-7).
__device__ __forceinline__ float tanh_fast(float x) {
    float e = __builtin_amdgcn_exp2f(x * 2.8853900817779268f);
    float q = __builtin_amdgcn_rcpf(e + 1.f);
    return fmaf(-2.f, q, 1.f);
}

// ---------------------------------------------------------------------------
// Pack W1 into MFMA B-fragment order as bf16 (+ zero emb, folded in).
// Fragment (kstep s 0..7, nfrag f 0..15): lane l, elem j holds
// W1[s*32 + (l>>4)*8 + j][f*16 + (l&15)].  Linear idx = ((s*16+f)*64+l)*8+j.
// ---------------------------------------------------------------------------
__global__ __launch_bounds__(256) void pack_w1(const float* __restrict__ W1,
                                               short* __restrict__ B0p,
                                               float* __restrict__ emb)
{
    int id = blockIdx.x * 256 + threadIdx.x;   // 0..65535
    int j = id & 7, l = (id >> 3) & 63, f = (id >> 9) & 15, s = id >> 13;
    int k = s * 32 + ((l >> 4) << 3) + j;
    int c = (f << 4) + (l & 15);
    B0p[id] = (short)f2bf(W1[k * HNF + c]);
    #pragma unroll
    for (int e = 0; e < 4; e++)
        emb[(size_t)e * 65536 + id] = 0.f;     // 4*65536 = 1024*256
}

// ---------------------------------------------------------------------------
// Kernel 1: 7168 blocks x 512 threads (8 waves), one 64x256 tile each.
// LDS 52KB -> 3 blocks/CU (24 waves). Staging is wave-self-paced (NO block
// barriers): 4 quarters; per quarter each wave DMAs its own 2 rows
// (global_load_lds w16, XOR-presw source), waits vmcnt(0) wave-locally,
// reads back via swizzled ds_read_b128 (conflict-free), cvt_pk to bf16,
// writes Abf with di^=(di>>8)&7 swizzle (write: spreads banks by kstep;
// read: wave-uniform XOR, stays conflict-free). B-fragments preloaded into
// registers before staging so the MFMA phase issues zero global loads.
// One barrier before MFMA, one before the cross-wave e2 reduce.
// ---------------------------------------------------------------------------
__global__ __launch_bounds__(512, 6) void fused_mlp_bf16(
    const float* __restrict__ gnn, const short* __restrict__ B0p,
    const float* __restrict__ b1, const float* __restrict__ W2,
    const float* __restrict__ b2,
    float* __restrict__ Dreg, float* __restrict__ Wreg, float* __restrict__ emb)
{
    __shared__ __align__(16) float stage[16 * 256];   // 16KB: 16 slots x 1KB
    __shared__ __align__(16) short Abf[16384];        // 32KB frag-linear bf16
    __shared__ float red0[8][64];
    __shared__ float red1[8][64];

    const int t = threadIdx.x;
    const int w = t >> 6, l = t & 63;
    const int batch = blockIdx.x / TILES_PER_BATCH;
    const int tile  = blockIdx.x % TILES_PER_BATCH;
    const long row0 = (long)batch * NN + (long)tile * BMV;

    // fragment decode
    const int frow = l & 15, fk = l >> 4;

    // ---- preload B fragments to registers (L2; fly under the DMA phase) ----
    short8 bfr[8][2];
    #pragma unroll
    for (int kk = 0; kk < 8; kk++)
        #pragma unroll
        for (int n = 0; n < 2; n++) {
            int nf = (w << 1) + n;
            bfr[kk][n] = *(const short8*)(B0p +
                ((size_t)((((kk << 4) + nf) << 6) | l) << 3));
        }

    // ---- staging: 4 quarters, wave-private rows/slots, no barriers ----
    const int rl  = l & 1;          // which of the wave's 2 rows
    const int cc  = (l >> 1) & 7;   // kstep this lane converts
    const int g   = l >> 4;         // k-subgroup (fk target)
    const int slA = w << 1;         // wave's stage slots: slA, slA+1
    const int sl  = slA | rl;

    #pragma unroll
    for (int q = 0; q < 4; q++) {
        if (q) asm volatile("s_waitcnt lgkmcnt(0)" ::: "memory");  // reads of q-1 done
        int rA = (q << 4) | slA, rB = rA | 1;
        long arA = row0 + rA; if (arA >= (long)TOT_ROWS) arA = TOT_ROWS - 1;
        long arB = row0 + rB; if (arB >= (long)TOT_ROWS) arB = TOT_ROWS - 1;
        // source chunk pre-swizzle: physical chunk l holds logical
        // L = (l&56) | ((l ^ (l>>3) ^ r) & 7)
        int LA = (l & 56) | ((l ^ (l >> 3) ^ rA) & 7);
        int LB = (l & 56) | ((l ^ (l >> 3) ^ rB) & 7);
        __builtin_amdgcn_global_load_lds(
            (const __attribute__((address_space(1))) unsigned*)(gnn + arA * HNF + (LA << 2)),
            (__attribute__((address_space(3))) unsigned*)(stage + (slA << 8)),
            16, 0, 0);
        __builtin_amdgcn_global_load_lds(
            (const __attribute__((address_space(1))) unsigned*)(gnn + arB * HNF + (LB << 2)),
            (__attribute__((address_space(3))) unsigned*)(stage + ((slA + 1) << 8)),
            16, 0, 0);
        asm volatile("s_waitcnt vmcnt(0)" ::: "memory");   // wave-local drain

        // convert: lane handles (row sl, kstep cc, subgroup g) = 8 floats
        int r = (q << 4) | sl;
        int p0 = (cc << 3) | (((g << 1) ^ cc ^ r) & 7);
        int p1 = (cc << 3) | ((((g << 1) | 1) ^ cc ^ r) & 7);
        float4 f0 = *(const float4*)(stage + (sl << 8) + (p0 << 2));
        float4 f1 = *(const float4*)(stage + (sl << 8) + (p1 << 2));
        uint4 pv;
        pv.x = pk_bf16(f0.x, f0.y); pv.y = pk_bf16(f0.z, f0.w);
        pv.z = pk_bf16(f1.x, f1.y); pv.w = pk_bf16(f1.z, f1.w);
        int di = (((cc << 2) + q) << 6) | (g << 4) | sl;   // mr = q
        *(uint4*)(Abf + ((size_t)(di ^ cc) << 3)) = pv;    // bank swizzle
    }
    __syncthreads();   // all waves' Abf writes visible

    // ---- MFMA loop: 8 k-steps x (4m x 2n) per wave, zero global loads ----
    float4v acc[4][2];
    #pragma unroll
    for (int m = 0; m < 4; m++)
        #pragma unroll
        for (int n = 0; n < 2; n++)
            acc[m][n] = (float4v){0.f, 0.f, 0.f, 0.f};

    #pragma unroll 2
    for (int kk = 0; kk < 8; ++kk) {
        short8 af[4];
        #pragma unroll
        for (int m = 0; m < 4; m++) {
            int di = ((((kk << 2) + m) << 6) | l) ^ kk;    // same swizzle
            af[m] = *(const short8*)(Abf + (size_t)di * 8);
        }
        #pragma unroll
        for (int m = 0; m < 4; m++)
            #pragma unroll
            for (int n = 0; n < 2; n++)
                acc[m][n] = __builtin_amdgcn_mfma_f32_16x16x32_bf16(af[m], bfr[kk][n], acc[m][n], 0, 0, 0);
    }

    // ---- epilogue: bias+relu, e2 row-dots, emb partials ----
    // C frag: col = (2w+n)*16 + (l&15), row = m*16 + (l>>4)*4 + j
    float w20[2], w21[2], b1v[2];
    #pragma unroll
    for (int n = 0; n < 2; n++) {
        int c2 = (((w << 1) + n) << 4) + frow;
        b1v[n] = b1[c2];
        w20[n] = W2[2 * c2];
        w21[n] = W2[2 * c2 + 1];
    }
    float ps0[4][4], ps1[4][4], embp[2] = {0.f, 0.f};
    #pragma unroll
    for (int m = 0; m < 4; m++)
        #pragma unroll
        for (int j = 0; j < 4; j++) { ps0[m][j] = 0.f; ps1[m][j] = 0.f; }

    #pragma unroll
    for (int m = 0; m < 4; m++)
        #pragma unroll
        for (int n = 0; n < 2; n++)
            #pragma unroll
            for (int j = 0; j < 4; j++) {
                float h = fmaxf(acc[m][n][j] + b1v[n], 0.f);
                ps0[m][j] += h * w20[n];
                ps1[m][j] += h * w21[n];
                int row = (m << 4) + (fk << 2) + j;
                if (row < BMV) embp[n] += h;     // exclude pad row
            }

    #pragma unroll
    for (int off = 1; off < 16; off <<= 1)
        #pragma unroll
        for (int m = 0; m < 4; m++)
            #pragma unroll
            for (int j = 0; j < 4; j++) {
                ps0[m][j] += __shfl_xor(ps0[m][j], off);
                ps1[m][j] += __shfl_xor(ps1[m][j], off);
            }
    if (frow == 0) {
        #pragma unroll
        for (int m = 0; m < 4; m++)
            #pragma unroll
            for (int j = 0; j < 4; j++) {
                int row = (m << 4) + (fk << 2) + j;
                red0[w][row] = ps0[m][j];
                red1[w][row] = ps1[m][j];
            }
    }

    #pragma unroll
    for (int n = 0; n < 2; n++) {
        embp[n] += __shfl_xor(embp[n], 16);
        embp[n] += __shfl_xor(embp[n], 32);
    }
    if (l < 16) {
        #pragma unroll
        for (int n = 0; n < 2; n++)
            atomicAdd(emb + (size_t)batch * 256 + (((w << 1) + n) << 4) + l, embp[n]);
    }

    __syncthreads();
    if (t < BMV) {
        float v0 = b2[0], v1 = b2[1];
        #pragma unroll
        for (int ww = 0; ww < 8; ww++) { v0 += red0[ww][t]; v1 += red1[ww][t]; }
        Dreg[row0 + t] = v0;    // raw e2 ch0 (symmetrized in recon)
        Wreg[row0 + t] = v1;
    }
}

// ---------------------------------------------------------------------------
// Kernel 2: fused symmetrize+softplus (writes D/W outputs) + register MDS
// recon. 1 block = 1 wave = 1 batch; lane i<21 owns row i. readlane
// broadcasts; 3-way split accumulators; W*D prefold; raw rsq/exp/rcp.
// ---------------------------------------------------------------------------
__global__ __launch_bounds__(64) void symrecon_kernel(
    float* __restrict__ Dreg, float* __restrict__ Wreg,
    const float* __restrict__ un, const float* __restrict__ xn,
    float* __restrict__ Xo)
{
    const int b = blockIdx.x, l = threadIdx.x;
    __shared__ float R0[NN], R1[NN];

    float* Db = Dreg + (size_t)b * NN;
    float* Wb = Wreg + (size_t)b * NN;
    for (int idx = l; idx < NN; idx += 64) { R0[idx] = Db[idx]; R1[idx] = Wb[idx]; }
    __syncthreads();

    const bool act = (l < NMAX);
    const int li = act ? l : 0;
    float Drow[NMAX], Wrow[NMAX], WD[NMAX];
    float rs = 0.f;
    #pragma unroll
    for (int q = 0; q < NMAX; q++) {
        float rd = R0[li * NMAX + q] + R0[q * NMAX + li];
        float rw = R1[li * NMAX + q] + R1[q * NMAX + li];
        float d = (q == li) ? 0.f : softplus_f(rd);
        float wv = softplus_f(rw);
        Drow[q] = act ? d : 0.f;
        Wrow[q] = act ? wv : 0.f;
        WD[q] = Wrow[q] * Drow[q];
        rs += Drow[q];
    }
    if (act) {
        #pragma unroll
        for (int q = 0; q < NMAX; q++) {
            Db[l * NMAX + q] = Drow[q];
            Wb[l * NMAX + q] = Wrow[q];
        }
    }

    // double-centering (lanes 21..31 zero => 32-wide butterfly suffices)
    float tot = rs;
    #pragma unroll
    for (int m = 1; m < 32; m <<= 1) tot += __shfl_xor(tot, m);
    const float mean = tot * (1.f / (float)NN);
    const float rsn = rs * (1.f / (float)NMAX);
    float Arow[NMAX];
    #pragma unroll
    for (int q = 0; q < NMAX; q++) {
        float rsq = bcast(rsn, q);
        float v = -0.5f * (Drow[q] - rsn - rsq + mean);
        Arow[q] = act ? v : 0.f;
    }

    // deflated power iteration: k=3 eigvecs, 10 steps each
    float xr[3] = {0.f, 0.f, 0.f};
    #pragma unroll
    for (int e = 0; e < 3; e++) {
        float u = act ? un[(size_t)b * 63 + e * NMAX + l] : 0.f;
        for (int s = 0; s < 10; s++) {
            float n2 = u * u;
            #pragma unroll
            for (int m = 1; m < 32; m <<= 1) n2 += __shfl_xor(n2, m);
            u *= fminf(__builtin_amdgcn_rsqf(n2), 1000.f);
            float a0 = 0.f, a1 = 0.f, a2 = 0.f;
            #pragma unroll
            for (int q = 0; q < NMAX; q++) {
                float uq = bcast(u, q);
                if ((q % 3) == 0)      a0 = fmaf(Arow[q], uq, a0);
                else if ((q % 3) == 1) a1 = fmaf(Arow[q], uq, a1);
                else                   a2 = fmaf(Arow[q], uq, a2);
            }
            u = act ? ((a0 + a1) + a2) : 0.f;
        }
        float e2 = u * u;
        #pragma unroll
        for (int m = 1; m < 32; m <<= 1) e2 += __shfl_xor(e2, m);
        u *= sqrtf(__builtin_amdgcn_rsqf(e2 + 0.01f));   // (e2+.01)^-0.25
        xr[e] = u;
        #pragma unroll
        for (int q = 0; q < NMAX; q++) Arow[q] = fmaf(-u, bcast(u, q), Arow[q]);
    }
    float x = xr[0], y = xr[1], z = xr[2];
    if (act) {
        x += xn[(size_t)b * 63 + l * 3 + 0];
        y += xn[(size_t)b * 63 + l * 3 + 1];
        z += xn[(size_t)b * 63 + l * 3 + 2];
    }

    // 100 clipped GD steps: registers + readlane; split accumulators (ILP)
    for (int tstep = 0; tstep < 100; tstep++) {
        float gx0=0.f,gx1=0.f,gx2=0.f, gy0=0.f,gy1=0.f,gy2=0.f,
              gz0=0.f,gz1=0.f,gz2=0.f;
        #pragma unroll
        for (int q = 0; q < NMAX; q++) {
            float dx = x - bcast(x, q);
            float dy = y - bcast(y, q);
            float dz = z - bcast(z, q);
            float s = fmaf(dx, dx, fmaf(dy, dy, fmaf(dz, dz, 0.01f)));
            float cm = fmaf(-Wrow[q], s, WD[q]);   // W*(D - s)
            if ((q % 3) == 0)      { gx0 = fmaf(cm,dx,gx0); gy0 = fmaf(cm,dy,gy0); gz0 = fmaf(cm,dz,gz0); }
            else if ((q % 3) == 1) { gx1 = fmaf(cm,dx,gx1); gy1 = fmaf(cm,dy,gy1); gz1 = fmaf(cm,dz,gz1); }
            else                   { gx2 = fmaf(cm,dx,gx2); gy2 = fmaf(cm,dy,gy2); gz2 = fmaf(cm,dz,gz2); }
        }
        float d0 = 0.8f * ((gx0 + gx1) + gx2);
        float d1 = 0.8f * ((gy0 + gy1) + gy2);
        float d2 = 0.8f * ((gz0 + gz1) + gz2);
        float ss = fmaf(d0, d0, fmaf(d1, d1, fmaf(d2, d2, 1e-3f)));
        float inv_sp = __builtin_amdgcn_rsqf(ss);
        float speed  = ss * inv_sp;
        float alpha  = fmaf(-0.049f, (float)tstep, 5.0f);
        float th     = tanh_fast(speed * __builtin_amdgcn_rcpf(alpha));
        float scale  = alpha * th * inv_sp;
        x = fmaf(d0, scale, x);
        y = fmaf(d1, scale, y);
        z = fmaf(d2, scale, z);
    }
    if (act) {
        Xo[(size_t)b * 63 + l * 3 + 0] = x;
        Xo[(size_t)b * 63 + l * 3 + 1] = y;
        Xo[(size_t)b * 63 + l * 3 + 2] = z;
    }
}

// ---------------------------------------------------------------------------
extern "C" void kernel_launch(void* const* d_in, const int* in_sizes, int n_in,
                              void* d_out, int out_size, void* d_ws, size_t ws_size,
                              hipStream_t stream) {
    const float* gnn = (const float*)d_in[0];
    const float* W1  = (const float*)d_in[1];
    const float* b1  = (const float*)d_in[2];
    const float* W2  = (const float*)d_in[3];
    const float* b2  = (const float*)d_in[4];
    const float* un  = (const float*)d_in[5];
    const float* xn  = (const float*)d_in[6];

    float* out  = (float*)d_out;
    float* Dreg = out;                                  // [1024*441]
    float* Wreg = out + (size_t)TOT_ROWS;               // [1024*441]
    float* emb  = out + (size_t)2 * TOT_ROWS;           // [1024*256]
    float* Xo   = out + (size_t)2 * TOT_ROWS + B_SZ*256;// [1024*63]

    short* B0p = (short*)d_ws;                          // 65536 bf16 (128KB)

    pack_w1<<<dim3(256), dim3(256), 0, stream>>>(W1, B0p, emb);

    fused_mlp_bf16<<<dim3(B_SZ * TILES_PER_BATCH), dim3(512), 0, stream>>>(
        gnn, B0p, b1, W2, b2, Dreg, Wreg, emb);

    symrecon_kernel<<<dim3(B_SZ), dim3(64), 0, stream>>>(Dreg, Wreg, un, xn, Xo);
}

// Round 10
// 292.105 us; speedup vs baseline: 2.4700x; 2.4700x over previous
//
#include <hip/hip_runtime.h>
#include <hip/hip_bf16.h>
#include <math.h>

#define B_SZ 1024
#define NMAX 21
#define NN 441            // 21*21
#define HNF 256
#define TOT_ROWS (B_SZ * NN)   // 451584
#define TILES_PER_BATCH 7      // 441 = 7*63
#define BMV 63                 // valid rows per tile (row 63 is pad)

typedef short short8 __attribute__((ext_vector_type(8)));
typedef float float4v __attribute__((ext_vector_type(4)));

__device__ __forceinline__ float softplus_f(float x) {
    return fmaxf(x, 0.f) + log1pf(expf(-fabsf(x)));
}

__device__ __forceinline__ unsigned short f2bf(float x) {
    union { float f; unsigned int u; } v; v.f = x;
    unsigned int r = v.u + 0x7FFFu + ((v.u >> 16) & 1u);   // RNE
    return (unsigned short)(r >> 16);
}

// hardware packed fp32->bf16 (v_cvt_pk_bf16_f32), RNE
__device__ __forceinline__ unsigned pk_bf16(float lo, float hi) {
    __hip_bfloat162 h = __float22bfloat162_rn(float2{lo, hi});
    return *reinterpret_cast<unsigned*>(&h);
}

// wave-uniform broadcast of lane q via SGPR (readlane), avoids ds_bpermute
__device__ __forceinline__ float bcast(float v, int q) {
    int i = __builtin_amdgcn_readlane(__builtin_bit_cast(int, v), q);
    return __builtin_bit_cast(float, i);
}

// fast tanh for x>=0: 1 - 2/(exp2(x*2log2e)+1). v_exp/v_rcp approx (~1e-7).
__device__ __forceinline__ float tanh_fast(float x) {
    float e = __builtin_amdgcn_exp2f(x * 2.8853900817779268f);
    float q = __builtin_amdgcn_rcpf(e + 1.f);
    return fmaf(-2.f, q, 1.f);
}

// ---------------------------------------------------------------------------
// Pack W1 into MFMA B-fragment order as bf16 (+ zero emb, folded in).
// Fragment (kstep s 0..7, nfrag f 0..15): lane l, elem j holds
// W1[s*32 + (l>>4)*8 + j][f*16 + (l&15)].  Linear idx = ((s*16+f)*64+l)*8+j.
// ---------------------------------------------------------------------------
__global__ __launch_bounds__(256) void pack_w1(const float* __restrict__ W1,
                                               short* __restrict__ B0p,
                                               float* __restrict__ emb)
{
    int id = blockIdx.x * 256 + threadIdx.x;   // 0..65535
    int j = id & 7, l = (id >> 3) & 63, f = (id >> 9) & 15, s = id >> 13;
    int k = s * 32 + ((l >> 4) << 3) + j;
    int c = (f << 4) + (l & 15);
    B0p[id] = (short)f2bf(W1[k * HNF + c]);
    #pragma unroll
    for (int e = 0; e < 4; e++)
        emb[(size_t)e * 65536 + id] = 0.f;     // 4*65536 = 1024*256
}

// ---------------------------------------------------------------------------
// Kernel 1 (= R8 structure + bank-balanced swizzles): 7168 blocks x 512
// threads (8 waves), one 64x256 tile each. Stage: global_load_lds width-16
// DMA of raw fp32 into 64KB LDS with XOR-pre-swizzled per-lane SOURCE
// addresses (j = (l&56)|((l^(l>>3)^r)&7)) so the convert pass's ds_read_b128
// is bank-BALANCED across all 8 four-bank groups (R8's version put all 64
// lanes of each read in one group). Convert: cvt_pk to bf16, write
// frag-linear overlaying the first 32KB, with di^kstep XOR so writes are
// balanced too; MFMA reads undo the same XOR (wave-uniform). LDS 68KB ->
// 2 blocks/CU x 8 waves = 16 waves/CU.
// ---------------------------------------------------------------------------
__global__ __launch_bounds__(512, 4) void fused_mlp_bf16(
    const float* __restrict__ gnn, const short* __restrict__ B0p,
    const float* __restrict__ b1, const float* __restrict__ W2,
    const float* __restrict__ b2,
    float* __restrict__ Dreg, float* __restrict__ Wreg, float* __restrict__ emb)
{
    __shared__ __align__(16) char ldsbuf[65536];
    float* stage = (float*)ldsbuf;     // [64][256] fp32, chunks xor-swizzled
    short* Abf   = (short*)ldsbuf;     // frag-linear bf16, overlays first 32KB
    __shared__ float red0[8][64];
    __shared__ float red1[8][64];

    const int t = threadIdx.x;
    const int w = t >> 6, l = t & 63;
    const int batch = blockIdx.x / TILES_PER_BATCH;
    const int tile  = blockIdx.x % TILES_PER_BATCH;
    const long row0 = (long)batch * NN + (long)tile * BMV;

    // ---- stage: wave w DMAs rows w*8 .. w*8+7, 1 KB (one row) per inst ----
    // physical chunk l of row r holds logical chunk (l&56)|((l^(l>>3)^r)&7)
    #pragma unroll
    for (int i = 0; i < 8; i++) {
        int r = (w << 3) + i;
        long ar = row0 + r;
        if (ar >= (long)TOT_ROWS) ar = TOT_ROWS - 1;   // pad row clamp
        int j = (l & 56) | ((l ^ (l >> 3) ^ r) & 7);   // source 16B chunk
        const float* gsrc = gnn + ar * HNF + (j << 2);
        __builtin_amdgcn_global_load_lds(
            (const __attribute__((address_space(1))) unsigned*)gsrc,
            (__attribute__((address_space(3))) unsigned*)(stage + (r << 8)),
            16, 0, 0);
    }
    __syncthreads();   // vmcnt(0) drain + barrier

    // ---- convert: thread owns (row r = t>>3, kstep c = t&7) ----
    const int r = t >> 3, c = t & 7;
    float4 fr[8];
    #pragma unroll
    for (int i = 0; i < 8; i++) {
        int pc = (c << 3) | ((i ^ c ^ r) & 7);         // physical chunk (swz read)
        fr[i] = *(const float4*)(stage + (r << 8) + (pc << 2));
    }
    __syncthreads();   // all fp32 reads done before bf16 overlay writes
    {
        const int mr = r >> 4;
        #pragma unroll
        for (int g = 0; g < 4; g++) {
            uint4 pv;
            pv.x = pk_bf16(fr[2*g].x,   fr[2*g].y);
            pv.y = pk_bf16(fr[2*g].z,   fr[2*g].w);
            pv.z = pk_bf16(fr[2*g+1].x, fr[2*g+1].y);
            pv.w = pk_bf16(fr[2*g+1].z, fr[2*g+1].w);
            int di = (((c << 2) + mr) << 6) + (g << 4) + (r & 15); // frag slot
            *(uint4*)(Abf + ((size_t)(di ^ c) << 3)) = pv;         // bank-balanced
        }
    }
    __syncthreads();

    // fragment decode for compute
    const int frow = l & 15;
    const int fk   = l >> 4;

    // ---- barrier-free MFMA loop: 8 k-steps x (4m x 2n) per wave ----
    float4v acc[4][2];
    #pragma unroll
    for (int m = 0; m < 4; m++)
        #pragma unroll
        for (int n = 0; n < 2; n++)
            acc[m][n] = (float4v){0.f, 0.f, 0.f, 0.f};

    #pragma unroll 2
    for (int kk = 0; kk < 8; ++kk) {
        short8 bf[2], af[4];
        #pragma unroll
        for (int n = 0; n < 2; n++) {
            int nf = (w << 1) + n;
            size_t off = (size_t)((((kk << 4) + nf) << 6) | l) << 3;
            bf[n] = *(const short8*)(B0p + off);
        }
        #pragma unroll
        for (int m = 0; m < 4; m++) {
            int di = ((((kk << 2) + m) << 6) | l) ^ kk;   // undo write swizzle
            af[m] = *(const short8*)(Abf + (size_t)di * 8);
        }
        #pragma unroll
        for (int m = 0; m < 4; m++)
            #pragma unroll
            for (int n = 0; n < 2; n++)
                acc[m][n] = __builtin_amdgcn_mfma_f32_16x16x32_bf16(af[m], bf[n], acc[m][n], 0, 0, 0);
    }

    // ---- epilogue: bias+relu, e2 row-dots, emb partials ----
    // C frag: col = (2w+n)*16 + (l&15), row = m*16 + (l>>4)*4 + j
    float w20[2], w21[2], b1v[2];
    #pragma unroll
    for (int n = 0; n < 2; n++) {
        int cc = (((w << 1) + n) << 4) + frow;
        b1v[n] = b1[cc];
        w20[n] = W2[2 * cc];
        w21[n] = W2[2 * cc + 1];
    }
    float ps0[4][4], ps1[4][4], embp[2] = {0.f, 0.f};
    #pragma unroll
    for (int m = 0; m < 4; m++)
        #pragma unroll
        for (int j = 0; j < 4; j++) { ps0[m][j] = 0.f; ps1[m][j] = 0.f; }

    #pragma unroll
    for (int m = 0; m < 4; m++)
        #pragma unroll
        for (int n = 0; n < 2; n++)
            #pragma unroll
            for (int j = 0; j < 4; j++) {
                float h = fmaxf(acc[m][n][j] + b1v[n], 0.f);
                ps0[m][j] += h * w20[n];
                ps1[m][j] += h * w21[n];
                int row = (m << 4) + (fk << 2) + j;
                if (row < BMV) embp[n] += h;     // exclude pad row
            }

    #pragma unroll
    for (int off = 1; off < 16; off <<= 1)
        #pragma unroll
        for (int m = 0; m < 4; m++)
            #pragma unroll
            for (int j = 0; j < 4; j++) {
                ps0[m][j] += __shfl_xor(ps0[m][j], off);
                ps1[m][j] += __shfl_xor(ps1[m][j], off);
            }
    if (frow == 0) {
        #pragma unroll
        for (int m = 0; m < 4; m++)
            #pragma unroll
            for (int j = 0; j < 4; j++) {
                int row = (m << 4) + (fk << 2) + j;
                red0[w][row] = ps0[m][j];
                red1[w][row] = ps1[m][j];
            }
    }

    #pragma unroll
    for (int n = 0; n < 2; n++) {
        embp[n] += __shfl_xor(embp[n], 16);
        embp[n] += __shfl_xor(embp[n], 32);
    }
    if (l < 16) {
        #pragma unroll
        for (int n = 0; n < 2; n++)
            atomicAdd(emb + (size_t)batch * 256 + (((w << 1) + n) << 4) + l, embp[n]);
    }

    __syncthreads();
    if (t < BMV) {
        float v0 = b2[0], v1 = b2[1];
        #pragma unroll
        for (int ww = 0; ww < 8; ww++) { v0 += red0[ww][t]; v1 += red1[ww][t]; }
        Dreg[row0 + t] = v0;    // raw e2 ch0 (symmetrized in recon)
        Wreg[row0 + t] = v1;
    }
}

// ---------------------------------------------------------------------------
// Kernel 2: fused symmetrize+softplus (writes D/W outputs) + register MDS
// recon. 1 block = 1 wave = 1 batch; lane i<21 owns row i. readlane
// broadcasts; 3-way split accumulators; W*D prefold; raw rsq/exp/rcp.
// ---------------------------------------------------------------------------
__global__ __launch_bounds__(64) void symrecon_kernel(
    float* __restrict__ Dreg, float* __restrict__ Wreg,
    const float* __restrict__ un, const float* __restrict__ xn,
    float* __restrict__ Xo)
{
    const int b = blockIdx.x, l = threadIdx.x;
    __shared__ float R0[NN], R1[NN];

    float* Db = Dreg + (size_t)b * NN;
    float* Wb = Wreg + (size_t)b * NN;
    for (int idx = l; idx < NN; idx += 64) { R0[idx] = Db[idx]; R1[idx] = Wb[idx]; }
    __syncthreads();

    const bool act = (l < NMAX);
    const int li = act ? l : 0;
    float Drow[NMAX], Wrow[NMAX], WD[NMAX];
    float rs = 0.f;
    #pragma unroll
    for (int q = 0; q < NMAX; q++) {
        float rd = R0[li * NMAX + q] + R0[q * NMAX + li];
        float rw = R1[li * NMAX + q] + R1[q * NMAX + li];
        float d = (q == li) ? 0.f : softplus_f(rd);
        float wv = softplus_f(rw);
        Drow[q] = act ? d : 0.f;
        Wrow[q] = act ? wv : 0.f;
        WD[q] = Wrow[q] * Drow[q];
        rs += Drow[q];
    }
    if (act) {
        #pragma unroll
        for (int q = 0; q < NMAX; q++) {
            Db[l * NMAX + q] = Drow[q];
            Wb[l * NMAX + q] = Wrow[q];
        }
    }

    // double-centering (lanes 21..31 zero => 32-wide butterfly suffices)
    float tot = rs;
    #pragma unroll
    for (int m = 1; m < 32; m <<= 1) tot += __shfl_xor(tot, m);
    const float mean = tot * (1.f / (float)NN);
    const float rsn = rs * (1.f / (float)NMAX);
    float Arow[NMAX];
    #pragma unroll
    for (int q = 0; q < NMAX; q++) {
        float rsq = bcast(rsn, q);
        float v = -0.5f * (Drow[q] - rsn - rsq + mean);
        Arow[q] = act ? v : 0.f;
    }

    // deflated power iteration: k=3 eigvecs, 10 steps each
    float xr[3] = {0.f, 0.f, 0.f};
    #pragma unroll
    for (int e = 0; e < 3; e++) {
        float u = act ? un[(size_t)b * 63 + e * NMAX + l] : 0.f;
        for (int s = 0; s < 10; s++) {
            float n2 = u * u;
            #pragma unroll
            for (int m = 1; m < 32; m <<= 1) n2 += __shfl_xor(n2, m);
            u *= fminf(__builtin_amdgcn_rsqf(n2), 1000.f);
            float a0 = 0.f, a1 = 0.f, a2 = 0.f;
            #pragma unroll
            for (int q = 0; q < NMAX; q++) {
                float uq = bcast(u, q);
                if ((q % 3) == 0)      a0 = fmaf(Arow[q], uq, a0);
                else if ((q % 3) == 1) a1 = fmaf(Arow[q], uq, a1);
                else                   a2 = fmaf(Arow[q], uq, a2);
            }
            u = act ? ((a0 + a1) + a2) : 0.f;
        }
        float e2 = u * u;
        #pragma unroll
        for (int m = 1; m < 32; m <<= 1) e2 += __shfl_xor(e2, m);
        u *= sqrtf(__builtin_amdgcn_rsqf(e2 + 0.01f));   // (e2+.01)^-0.25
        xr[e] = u;
        #pragma unroll
        for (int q = 0; q < NMAX; q++) Arow[q] = fmaf(-u, bcast(u, q), Arow[q]);
    }
    float x = xr[0], y = xr[1], z = xr[2];
    if (act) {
        x += xn[(size_t)b * 63 + l * 3 + 0];
        y += xn[(size_t)b * 63 + l * 3 + 1];
        z += xn[(size_t)b * 63 + l * 3 + 2];
    }

    // 100 clipped GD steps: registers + readlane; split accumulators (ILP)
    for (int tstep = 0; tstep < 100; tstep++) {
        float gx0=0.f,gx1=0.f,gx2=0.f, gy0=0.f,gy1=0.f,gy2=0.f,
              gz0=0.f,gz1=0.f,gz2=0.f;
        #pragma unroll
        for (int q = 0; q < NMAX; q++) {
            float dx = x - bcast(x, q);
            float dy = y - bcast(y, q);
            float dz = z - bcast(z, q);
            float s = fmaf(dx, dx, fmaf(dy, dy, fmaf(dz, dz, 0.01f)));
            float cm = fmaf(-Wrow[q], s, WD[q]);   // W*(D - s)
            if ((q % 3) == 0)      { gx0 = fmaf(cm,dx,gx0); gy0 = fmaf(cm,dy,gy0); gz0 = fmaf(cm,dz,gz0); }
            else if ((q % 3) == 1) { gx1 = fmaf(cm,dx,gx1); gy1 = fmaf(cm,dy,gy1); gz1 = fmaf(cm,dz,gz1); }
            else                   { gx2 = fmaf(cm,dx,gx2); gy2 = fmaf(cm,dy,gy2); gz2 = fmaf(cm,dz,gz2); }
        }
        float d0 = 0.8f * ((gx0 + gx1) + gx2);
        float d1 = 0.8f * ((gy0 + gy1) + gy2);
        float d2 = 0.8f * ((gz0 + gz1) + gz2);
        float ss = fmaf(d0, d0, fmaf(d1, d1, fmaf(d2, d2, 1e-3f)));
        float inv_sp = __builtin_amdgcn_rsqf(ss);
        float speed  = ss * inv_sp;
        float alpha  = fmaf(-0.049f, (float)tstep, 5.0f);
        float th     = tanh_fast(speed * __builtin_amdgcn_rcpf(alpha));
        float scale  = alpha * th * inv_sp;
        x = fmaf(d0, scale, x);
        y = fmaf(d1, scale, y);
        z = fmaf(d2, scale, z);
    }
    if (act) {
        Xo[(size_t)b * 63 + l * 3 + 0] = x;
        Xo[(size_t)b * 63 + l * 3 + 1] = y;
        Xo[(size_t)b * 63 + l * 3 + 2] = z;
    }
}

// ---------------------------------------------------------------------------
extern "C" void kernel_launch(void* const* d_in, const int* in_sizes, int n_in,
                              void* d_out, int out_size, void* d_ws, size_t ws_size,
                              hipStream_t stream) {
    const float* gnn = (const float*)d_in[0];
    const float* W1  = (const float*)d_in[1];
    const float* b1  = (const float*)d_in[2];
    const float* W2  = (const float*)d_in[3];
    const float* b2  = (const float*)d_in[4];
    const float* un  = (const float*)d_in[5];
    const float* xn  = (const float*)d_in[6];

    float* out  = (float*)d_out;
    float* Dreg = out;                                  // [1024*441]
    float* Wreg = out + (size_t)TOT_ROWS;               // [1024*441]
    float* emb  = out + (size_t)2 * TOT_ROWS;           // [1024*256]
    float* Xo   = out + (size_t)2 * TOT_ROWS + B_SZ*256;// [1024*63]

    short* B0p = (short*)d_ws;                          // 65536 bf16 (128KB)

    pack_w1<<<dim3(256), dim3(256), 0, stream>>>(W1, B0p, emb);

    fused_mlp_bf16<<<dim3(B_SZ * TILES_PER_BATCH), dim3(512), 0, stream>>>(
        gnn, B0p, b1, W2, b2, Dreg, Wreg, emb);

    symrecon_kernel<<<dim3(B_SZ), dim3(64), 0, stream>>>(Dreg, Wreg, un, xn, Xo);
}

// Round 11
// 267.132 us; speedup vs baseline: 2.7009x; 1.0935x over previous
//
#include <hip/hip_runtime.h>
#include <hip/hip_bf16.h>
#include <math.h>

#define B_SZ 1024
#define NMAX 21
#define NN 441            // 21*21
#define HNF 256
#define TOT_ROWS (B_SZ * NN)   // 451584
#define TILES_PER_BATCH 7      // 441 = 7*63
#define BMV 63                 // valid rows per tile (row 63 is pad)

typedef short short8 __attribute__((ext_vector_type(8)));
typedef float float4v __attribute__((ext_vector_type(4)));

__device__ __forceinline__ unsigned short f2bf(float x) {
    union { float f; unsigned int u; } v; v.f = x;
    unsigned int r = v.u + 0x7FFFu + ((v.u >> 16) & 1u);   // RNE
    return (unsigned short)(r >> 16);
}

// hardware packed fp32->bf16 (v_cvt_pk_bf16_f32), RNE
__device__ __forceinline__ unsigned pk_bf16(float lo, float hi) {
    __hip_bfloat162 h = __float22bfloat162_rn(float2{lo, hi});
    return *reinterpret_cast<unsigned*>(&h);
}

// fast softplus: max(x,0) + ln2*log2(1 + exp2(-|x|*log2e)), raw v_exp/v_log
__device__ __forceinline__ float softplus_fast(float x) {
    float e = __builtin_amdgcn_exp2f(-fabsf(x) * 1.44269504088896f);
    float lg = __builtin_amdgcn_logf(1.f + e);
    return fmaxf(x, 0.f) + 0.69314718055995f * lg;
}

// fast tanh for x>=0: 1 - 2/(exp2(x*2log2e)+1). v_exp/v_rcp approx (~1e-7).
__device__ __forceinline__ float tanh_fast(float x) {
    float e = __builtin_amdgcn_exp2f(x * 2.8853900817779268f);
    float q = __builtin_amdgcn_rcpf(e + 1.f);
    return fmaf(-2.f, q, 1.f);
}

// ---------------------------------------------------------------------------
// Pack W1 into MFMA B-fragment order as bf16 (+ zero emb, folded in).
// Fragment (kstep s 0..7, nfrag f 0..15): lane l, elem j holds
// W1[s*32 + (l>>4)*8 + j][f*16 + (l&15)].  Linear idx = ((s*16+f)*64+l)*8+j.
// ---------------------------------------------------------------------------
__global__ __launch_bounds__(256) void pack_w1(const float* __restrict__ W1,
                                               short* __restrict__ B0p,
                                               float* __restrict__ emb)
{
    int id = blockIdx.x * 256 + threadIdx.x;   // 0..65535
    int j = id & 7, l = (id >> 3) & 63, f = (id >> 9) & 15, s = id >> 13;
    int k = s * 32 + ((l >> 4) << 3) + j;
    int c = (f << 4) + (l & 15);
    B0p[id] = (short)f2bf(W1[k * HNF + c]);
    #pragma unroll
    for (int e = 0; e < 4; e++)
        emb[(size_t)e * 65536 + id] = 0.f;     // 4*65536 = 1024*256
}

// ---------------------------------------------------------------------------
// Kernel 1 (unchanged from R10, best measured): 7168 blocks x 512 threads.
// global_load_lds w16 DMA with XOR-presw source; bank-balanced convert
// (ds_read swz p = (c<<3)|((i^c^r)&7)); Abf frag-linear with di^kstep XOR on
// write and read. LDS 68KB -> 2 blocks/CU x 8 waves.
// ---------------------------------------------------------------------------
__global__ __launch_bounds__(512, 4) void fused_mlp_bf16(
    const float* __restrict__ gnn, const short* __restrict__ B0p,
    const float* __restrict__ b1, const float* __restrict__ W2,
    const float* __restrict__ b2,
    float* __restrict__ Dreg, float* __restrict__ Wreg, float* __restrict__ emb)
{
    __shared__ __align__(16) char ldsbuf[65536];
    float* stage = (float*)ldsbuf;     // [64][256] fp32, chunks xor-swizzled
    short* Abf   = (short*)ldsbuf;     // frag-linear bf16, overlays first 32KB
    __shared__ float red0[8][64];
    __shared__ float red1[8][64];

    const int t = threadIdx.x;
    const int w = t >> 6, l = t & 63;
    const int batch = blockIdx.x / TILES_PER_BATCH;
    const int tile  = blockIdx.x % TILES_PER_BATCH;
    const long row0 = (long)batch * NN + (long)tile * BMV;

    #pragma unroll
    for (int i = 0; i < 8; i++) {
        int r = (w << 3) + i;
        long ar = row0 + r;
        if (ar >= (long)TOT_ROWS) ar = TOT_ROWS - 1;   // pad row clamp
        int j = (l & 56) | ((l ^ (l >> 3) ^ r) & 7);   // source 16B chunk
        const float* gsrc = gnn + ar * HNF + (j << 2);
        __builtin_amdgcn_global_load_lds(
            (const __attribute__((address_space(1))) unsigned*)gsrc,
            (__attribute__((address_space(3))) unsigned*)(stage + (r << 8)),
            16, 0, 0);
    }
    __syncthreads();   // vmcnt(0) drain + barrier

    const int r = t >> 3, c = t & 7;
    float4 fr[8];
    #pragma unroll
    for (int i = 0; i < 8; i++) {
        int pc = (c << 3) | ((i ^ c ^ r) & 7);         // physical chunk (swz read)
        fr[i] = *(const float4*)(stage + (r << 8) + (pc << 2));
    }
    __syncthreads();   // all fp32 reads done before bf16 overlay writes
    {
        const int mr = r >> 4;
        #pragma unroll
        for (int g = 0; g < 4; g++) {
            uint4 pv;
            pv.x = pk_bf16(fr[2*g].x,   fr[2*g].y);
            pv.y = pk_bf16(fr[2*g].z,   fr[2*g].w);
            pv.z = pk_bf16(fr[2*g+1].x, fr[2*g+1].y);
            pv.w = pk_bf16(fr[2*g+1].z, fr[2*g+1].w);
            int di = (((c << 2) + mr) << 6) + (g << 4) + (r & 15); // frag slot
            *(uint4*)(Abf + ((size_t)(di ^ c) << 3)) = pv;         // bank-balanced
        }
    }
    __syncthreads();

    const int frow = l & 15;
    const int fk   = l >> 4;

    float4v acc[4][2];
    #pragma unroll
    for (int m = 0; m < 4; m++)
        #pragma unroll
        for (int n = 0; n < 2; n++)
            acc[m][n] = (float4v){0.f, 0.f, 0.f, 0.f};

    #pragma unroll 2
    for (int kk = 0; kk < 8; ++kk) {
        short8 bf[2], af[4];
        #pragma unroll
        for (int n = 0; n < 2; n++) {
            int nf = (w << 1) + n;
            size_t off = (size_t)((((kk << 4) + nf) << 6) | l) << 3;
            bf[n] = *(const short8*)(B0p + off);
        }
        #pragma unroll
        for (int m = 0; m < 4; m++) {
            int di = ((((kk << 2) + m) << 6) | l) ^ kk;   // undo write swizzle
            af[m] = *(const short8*)(Abf + (size_t)di * 8);
        }
        #pragma unroll
        for (int m = 0; m < 4; m++)
            #pragma unroll
            for (int n = 0; n < 2; n++)
                acc[m][n] = __builtin_amdgcn_mfma_f32_16x16x32_bf16(af[m], bf[n], acc[m][n], 0, 0, 0);
    }

    float w20[2], w21[2], b1v[2];
    #pragma unroll
    for (int n = 0; n < 2; n++) {
        int cc = (((w << 1) + n) << 4) + frow;
        b1v[n] = b1[cc];
        w20[n] = W2[2 * cc];
        w21[n] = W2[2 * cc + 1];
    }
    float ps0[4][4], ps1[4][4], embp[2] = {0.f, 0.f};
    #pragma unroll
    for (int m = 0; m < 4; m++)
        #pragma unroll
        for (int j = 0; j < 4; j++) { ps0[m][j] = 0.f; ps1[m][j] = 0.f; }

    #pragma unroll
    for (int m = 0; m < 4; m++)
        #pragma unroll
        for (int n = 0; n < 2; n++)
            #pragma unroll
            for (int j = 0; j < 4; j++) {
                float h = fmaxf(acc[m][n][j] + b1v[n], 0.f);
                ps0[m][j] += h * w20[n];
                ps1[m][j] += h * w21[n];
                int row = (m << 4) + (fk << 2) + j;
                if (row < BMV) embp[n] += h;     // exclude pad row
            }

    #pragma unroll
    for (int off = 1; off < 16; off <<= 1)
        #pragma unroll
        for (int m = 0; m < 4; m++)
            #pragma unroll
            for (int j = 0; j < 4; j++) {
                ps0[m][j] += __shfl_xor(ps0[m][j], off);
                ps1[m][j] += __shfl_xor(ps1[m][j], off);
            }
    if (frow == 0) {
        #pragma unroll
        for (int m = 0; m < 4; m++)
            #pragma unroll
            for (int j = 0; j < 4; j++) {
                int row = (m << 4) + (fk << 2) + j;
                red0[w][row] = ps0[m][j];
                red1[w][row] = ps1[m][j];
            }
    }

    #pragma unroll
    for (int n = 0; n < 2; n++) {
        embp[n] += __shfl_xor(embp[n], 16);
        embp[n] += __shfl_xor(embp[n], 32);
    }
    if (l < 16) {
        #pragma unroll
        for (int n = 0; n < 2; n++)
            atomicAdd(emb + (size_t)batch * 256 + (((w << 1) + n) << 4) + l, embp[n]);
    }

    __syncthreads();
    if (t < BMV) {
        float v0 = b2[0], v1 = b2[1];
        #pragma unroll
        for (int ww = 0; ww < 8; ww++) { v0 += red0[ww][t]; v1 += red1[ww][t]; }
        Dreg[row0 + t] = v0;    // raw e2 ch0 (symmetrized in recon)
        Wreg[row0 + t] = v1;
    }
}

// ---------------------------------------------------------------------------
// Kernel 2 (v3): sym+softplus + register MDS recon, SPLIT-Q across lane
// halves. Lane (i, h) = lanes i and i+32 (i<21) both own point i; half h
// covers q = 11*h + j, j=0..10 (h1's q=21 slot is zero-weighted padding).
// Cross-point broadcasts via LDS same-address reads (LDS pipe, parallel to
// VALU; single-wave program order makes write->read safe, no barriers).
// Gradient halves combined with one shfl_xor(32) per coordinate.
// ---------------------------------------------------------------------------
__global__ __launch_bounds__(64) void symrecon_kernel(
    float* __restrict__ Dreg, float* __restrict__ Wreg,
    const float* __restrict__ un, const float* __restrict__ xn,
    float* __restrict__ Xo)
{
    const int b = blockIdx.x, l = threadIdx.x;
    __shared__ float R0[NN], R1[NN];
    __shared__ float Rs[22], Us[22], Xs[3][22];

    float* Db = Dreg + (size_t)b * NN;
    float* Wb = Wreg + (size_t)b * NN;
    for (int idx = l; idx < NN; idx += 64) { R0[idx] = Db[idx]; R1[idx] = Wb[idx]; }
    if (l == 0) { Rs[21] = 0.f; Us[21] = 0.f; Xs[0][21] = 0.f; Xs[1][21] = 0.f; Xs[2][21] = 0.f; }
    __syncthreads();

    const int half = l >> 5;          // 0: q 0..10, 1: q 11..20 (+pad 21)
    const int li   = l & 31;          // point index
    const bool act = li < NMAX;
    const int li0  = act ? li : 0;
    const int q0   = half * 11;

    // ---- symmetrize + softplus, half-row per lane ----
    float Drow[11], Wrow[11], WD[11];
    float rsh = 0.f;
    #pragma unroll
    for (int j = 0; j < 11; j++) {
        int q = q0 + j;
        bool v = act && (q < NMAX);
        int qc = v ? q : 0;
        float rd = R0[li0 * NMAX + qc] + R0[qc * NMAX + li0];
        float rw = R1[li0 * NMAX + qc] + R1[qc * NMAX + li0];
        float d  = (v && q != li) ? softplus_fast(rd) : 0.f;
        float wv = v ? softplus_fast(rw) : 0.f;
        Drow[j] = d; Wrow[j] = wv; WD[j] = wv * d;
        rsh += d;
    }
    if (act) {
        #pragma unroll
        for (int j = 0; j < 11; j++) {
            int q = q0 + j;
            if (q < NMAX) {
                Db[li * NMAX + q] = Drow[j];
                Wb[li * NMAX + q] = Wrow[j];
            }
        }
    }

    // ---- double-centering ----
    float rsf = rsh + __shfl_xor(rsh, 32);   // full row sum for point li
    float tot = rsh;
    #pragma unroll
    for (int m = 1; m < 64; m <<= 1) tot += __shfl_xor(tot, m);
    const float mean = tot * (1.f / (float)NN);
    const float rsn  = rsf * (1.f / (float)NMAX);
    if (act && half == 0) Rs[li] = rsn;      // broadcast table (wave-ordered)
    float Arow[11];
    #pragma unroll
    for (int j = 0; j < 11; j++) {
        int q = q0 + j;
        bool v = act && (q < NMAX);
        float rsq = Rs[q];                   // LDS broadcast (pad q=21 -> 0)
        Arow[j] = v ? -0.5f * (Drow[j] - rsn - rsq + mean) : 0.f;
    }

    // ---- deflated power iteration: k=3 eigvecs, 10 steps each ----
    float xc[3];
    #pragma unroll
    for (int e = 0; e < 3; e++) {
        float u = act ? un[(size_t)b * 63 + e * NMAX + li] : 0.f;
        for (int s = 0; s < 10; s++) {
            float n2 = (act && half == 0) ? u * u : 0.f;
            #pragma unroll
            for (int m = 1; m < 64; m <<= 1) n2 += __shfl_xor(n2, m);
            u *= fminf(__builtin_amdgcn_rsqf(n2), 1000.f);
            if (act && half == 0) Us[li] = u;
            float a = 0.f;
            #pragma unroll
            for (int j = 0; j < 11; j++) a = fmaf(Arow[j], Us[q0 + j], a);
            a += __shfl_xor(a, 32);
            u = act ? a : 0.f;
        }
        float e2 = (act && half == 0) ? u * u : 0.f;
        #pragma unroll
        for (int m = 1; m < 64; m <<= 1) e2 += __shfl_xor(e2, m);
        u *= sqrtf(__builtin_amdgcn_rsqf(e2 + 0.01f));   // (e2+.01)^-0.25
        xc[e] = u;
        if (act && half == 0) Us[li] = u;
        #pragma unroll
        for (int j = 0; j < 11; j++) Arow[j] = fmaf(-u, Us[q0 + j], Arow[j]);
    }
    float x = xc[0], y = xc[1], z = xc[2];
    if (act) {
        x += xn[(size_t)b * 63 + li * 3 + 0];
        y += xn[(size_t)b * 63 + li * 3 + 1];
        z += xn[(size_t)b * 63 + li * 3 + 2];
    }
    if (act && half == 0) { Xs[0][li] = x; Xs[1][li] = y; Xs[2][li] = z; }

    // ---- 100 clipped GD steps: half-q per lane, LDS X broadcasts ----
    for (int tstep = 0; tstep < 100; tstep++) {
        float gx = 0.f, gy = 0.f, gz = 0.f;
        #pragma unroll
        for (int j = 0; j < 11; j++) {
            int q = q0 + j;
            float dx = x - Xs[0][q];
            float dy = y - Xs[1][q];
            float dz = z - Xs[2][q];
            float s  = fmaf(dx, dx, fmaf(dy, dy, fmaf(dz, dz, 0.01f)));
            float cm = fmaf(-Wrow[j], s, WD[j]);   // W*(D - s), pad -> 0
            gx = fmaf(cm, dx, gx);
            gy = fmaf(cm, dy, gy);
            gz = fmaf(cm, dz, gz);
        }
        gx += __shfl_xor(gx, 32);
        gy += __shfl_xor(gy, 32);
        gz += __shfl_xor(gz, 32);
        float d0 = 0.8f * gx, d1 = 0.8f * gy, d2 = 0.8f * gz;
        float ss = fmaf(d0, d0, fmaf(d1, d1, fmaf(d2, d2, 1e-3f)));
        float inv_sp = __builtin_amdgcn_rsqf(ss);
        float speed  = ss * inv_sp;
        float alpha  = fmaf(-0.049f, (float)tstep, 5.0f);
        float th     = tanh_fast(speed * __builtin_amdgcn_rcpf(alpha));
        float scale  = alpha * th * inv_sp;
        x = fmaf(d0, scale, x);
        y = fmaf(d1, scale, y);
        z = fmaf(d2, scale, z);
        if (act && half == 0) { Xs[0][li] = x; Xs[1][li] = y; Xs[2][li] = z; }
    }
    if (act && half == 0) {
        Xo[(size_t)b * 63 + li * 3 + 0] = x;
        Xo[(size_t)b * 63 + li * 3 + 1] = y;
        Xo[(size_t)b * 63 + li * 3 + 2] = z;
    }
}

// ---------------------------------------------------------------------------
extern "C" void kernel_launch(void* const* d_in, const int* in_sizes, int n_in,
                              void* d_out, int out_size, void* d_ws, size_t ws_size,
                              hipStream_t stream) {
    const float* gnn = (const float*)d_in[0];
    const float* W1  = (const float*)d_in[1];
    const float* b1  = (const float*)d_in[2];
    const float* W2  = (const float*)d_in[3];
    const float* b2  = (const float*)d_in[4];
    const float* un  = (const float*)d_in[5];
    const float* xn  = (const float*)d_in[6];

    float* out  = (float*)d_out;
    float* Dreg = out;                                  // [1024*441]
    float* Wreg = out + (size_t)TOT_ROWS;               // [1024*441]
    float* emb  = out + (size_t)2 * TOT_ROWS;           // [1024*256]
    float* Xo   = out + (size_t)2 * TOT_ROWS + B_SZ*256;// [1024*63]

    short* B0p = (short*)d_ws;                          // 65536 bf16 (128KB)

    pack_w1<<<dim3(256), dim3(256), 0, stream>>>(W1, B0p, emb);

    fused_mlp_bf16<<<dim3(B_SZ * TILES_PER_BATCH), dim3(512), 0, stream>>>(
        gnn, B0p, b1, W2, b2, Dreg, Wreg, emb);

    symrecon_kernel<<<dim3(B_SZ), dim3(64), 0, stream>>>(Dreg, Wreg, un, xn, Xo);
}